// Round 1
// baseline (694.660 us; speedup 1.0000x reference)
//
#include <hip/hip_runtime.h>
#include <hip/hip_bf16.h>
#include <stdint.h>

#define AS1 __attribute__((address_space(1)))
#define AS3 __attribute__((address_space(3)))

typedef __bf16 bf16x8 __attribute__((ext_vector_type(8)));
typedef float floatx4 __attribute__((ext_vector_type(4)));

static constexpr int NTOK = 4096;   // B*T
static constexpr int H    = 1024;
static constexpr int DFF  = 4096;
static constexpr int E    = 8;
static constexpr int BN   = 128;
static constexpr int RBMAX = 72;    // max 128-row tiles: ceil((8192+7*127)/128)=71

// ---- workspace layout (bytes) ----
static constexpr size_t OFF_WS     = 0;                      // 67,108,864  shuffled bf16 weights (w1 then w2)
static constexpr size_t OFF_XCS    = 67108864;               // 18,874,368  Xc (gemm1 A), reused as P0 by gemm2
static constexpr size_t OFF_HS     = 85983232;               // 75,497,472  shuffled bf16 hidden
static constexpr size_t OFF_P1     = 161480704;              // 18,874,368  split-K partial 1 (bf16)
static constexpr size_t OFF_RTIDX  = 180355072;              // 32 KB
static constexpr size_t OFF_RTW    = 180387840;              // 32 KB
static constexpr size_t OFF_PTOK   = 180420608;              // 36 KB
static constexpr size_t OFF_PW     = 180457472;              // 36 KB
static constexpr size_t OFF_TOKPOS = 180494336;              // 32 KB
static constexpr size_t OFF_CNT    = 180527104;              // counts(8)+cursors(8)+offs(9)
static constexpr size_t WS_NEED    = 180527232;

__device__ __forceinline__ unsigned short f2bf(float f) {
    __bf16 b = (__bf16)f;
    return __builtin_bit_cast(unsigned short, b);
}
__device__ __forceinline__ float bf2f(unsigned short u) {
    unsigned int v = ((unsigned int)u) << 16;
    return __builtin_bit_cast(float, v);
}

__device__ __forceinline__ void gload16(const void* g, void* l) {
    // dest = wave-uniform lds base; HW scatters lane i at base + i*16
    __builtin_amdgcn_global_load_lds((AS1 void*)g, (AS3 void*)l, 16, 0, 0);
}

// ---------------- router: fp32 logits, top-2, softmax ----------------
__global__ __launch_bounds__(256) void k_router(const float* __restrict__ x,
                                                const float* __restrict__ rw,
                                                int* __restrict__ rt_idx,
                                                float* __restrict__ rt_w,
                                                int* __restrict__ counts) {
    const int wv = threadIdx.x >> 6, ln = threadIdx.x & 63;
    const int t = blockIdx.x * 4 + wv;
    const float* xr = x + (size_t)t * H + ln * 4;
    float4 xv[4];
#pragma unroll
    for (int c = 0; c < 4; ++c) xv[c] = *(const float4*)(xr + c * 256);
    float lg[E];
#pragma unroll
    for (int e = 0; e < E; ++e) {
        const float* rr = rw + (size_t)e * H + ln * 4;
        float acc = 0.f;
#pragma unroll
        for (int c = 0; c < 4; ++c) {
            float4 rv = *(const float4*)(rr + c * 256);
            acc += xv[c].x * rv.x + xv[c].y * rv.y + xv[c].z * rv.z + xv[c].w * rv.w;
        }
#pragma unroll
        for (int s = 32; s > 0; s >>= 1) acc += __shfl_xor(acc, s, 64);
        lg[e] = acc;
    }
    if (ln == 0) {
        int i0 = 0; float v0 = lg[0];
#pragma unroll
        for (int e = 1; e < E; ++e) if (lg[e] > v0) { v0 = lg[e]; i0 = e; }
        int i1 = -1; float v1 = -INFINITY;
#pragma unroll
        for (int e = 0; e < E; ++e) if (e != i0 && lg[e] > v1) { v1 = lg[e]; i1 = e; }
        float e1 = expf(v1 - v0);
        float inv = 1.f / (1.f + e1);
        rt_idx[2 * t] = i0; rt_idx[2 * t + 1] = i1;
        rt_w[2 * t] = inv;  rt_w[2 * t + 1] = e1 * inv;
        atomicAdd(&counts[i0], 1);
        atomicAdd(&counts[i1], 1);
    }
}

// ---------------- padded prefix offsets ----------------
__global__ void k_offsets(const int* __restrict__ counts, int* __restrict__ offs) {
    if (threadIdx.x == 0) {
        int o = 0;
        for (int e = 0; e < E; ++e) { offs[e] = o; o += (counts[e] + 127) & ~127; }
        offs[E] = o;
    }
}

// ---------------- scatter pairs into expert segments ----------------
__global__ __launch_bounds__(256) void k_scatter(const int* __restrict__ rt_idx,
                                                 const float* __restrict__ rt_w,
                                                 const int* __restrict__ offs,
                                                 int* __restrict__ cursors,
                                                 int* __restrict__ pair_tok,
                                                 float* __restrict__ pair_w,
                                                 int* __restrict__ tok_pos) {
    int t = blockIdx.x * 256 + threadIdx.x;
    if (t >= NTOK) return;
    for (int k = 0; k < 2; ++k) {
        int e = rt_idx[2 * t + k];
        int p = atomicAdd(&cursors[e], 1);
        int pos = offs[e] + p;
        pair_tok[pos] = t;
        pair_w[pos] = rt_w[2 * t + k];
        tok_pos[2 * t + k] = pos;
    }
}

// ---------------- gather token rows -> bf16, octet-shuffled ----------------
// Xc_s[rb][kb][m][kq][j] = x[tok(pos)][kb*32+kq*8+j],  pos = rb*128+m ; pad rows = 0
__global__ __launch_bounds__(256) void k_gather(const float* __restrict__ x,
                                                const int* __restrict__ offs,
                                                const int* __restrict__ counts,
                                                const int* __restrict__ pair_tok,
                                                unsigned short* __restrict__ xcs) {
    int pos = blockIdx.x;
    if (pos >= offs[E]) return;
    int e = 0;
    while (e < E - 1 && pos >= offs[e + 1]) ++e;
    bool valid = (pos - offs[e]) < counts[e];
    int tok = valid ? pair_tok[pos] : 0;
    int k0 = threadIdx.x * 4;
    float4 xv = valid ? *(const float4*)(x + (size_t)tok * H + k0)
                      : make_float4(0.f, 0.f, 0.f, 0.f);
    ushort4 o;
    o.x = f2bf(xv.x); o.y = f2bf(xv.y); o.z = f2bf(xv.z); o.w = f2bf(xv.w);
    int rb = pos >> 7, m = pos & 127;
    size_t idx = (((size_t)(rb * 32 + (k0 >> 5)) * 128 + m) * 32) + (((k0 >> 3) & 3) << 3) + (k0 & 7);
    *(ushort4*)(xcs + idx) = o;
}

// ---------------- weight convert fp32 -> bf16, octet-shuffled ----------------
// Ws[e][kb][n][kq][j] = w[e][kb*32+kq*8+j][n]
// Coalesced: load 32x128 fp32 panel via float4 (contiguous 512B per 32 lanes),
// transpose through LDS, store contiguous uint4 octets.
template <int K, int N>
__global__ __launch_bounds__(256) void k_convert(const float* __restrict__ w,
                                                 unsigned short* __restrict__ ws) {
    constexpr int KB = K / 32, NC = N / 128;
    const int bid = blockIdx.x;
    const int nc = bid % NC, kb = (bid / NC) % KB, e = bid / (NC * KB);
    const int n0 = nc * 128;
    __shared__ float lp[32][128];
    const int tid = threadIdx.x;
    {
        const int kr = tid >> 5;          // 0..7
        const int c4 = (tid & 31) * 4;    // 0,4,...,124
        const float* src = w + (size_t)(e * K + kb * 32 + kr) * N + n0 + c4;
#pragma unroll
        for (int c = 0; c < 4; ++c)
            *(float4*)&lp[kr + 8 * c][c4] = *(const float4*)(src + (size_t)(8 * c) * N);
    }
    __syncthreads();
    const size_t base = ((size_t)(e * KB + kb) * N + n0) * 4;   // octet index
#pragma unroll
    for (int it = 0; it < 2; ++it) {
        const int item = it * 256 + tid;
        const int nl = item >> 2, kq = item & 3;
        union { unsigned short us[8]; uint4 v; } u;
#pragma unroll
        for (int j = 0; j < 8; ++j) u.us[j] = f2bf(lp[kq * 8 + j][nl]);
        *(uint4*)(ws + (base + (size_t)nl * 4 + kq) * 8) = u.v;
    }
}

// ---------------- GEMM1: Xc[8448x1024] x W1[e][1024x4096] -> gelu -> Hs ----------------
// A[m][k=quad*8+j] lane m=lane&15 ; B[k][n=lane&15] ; D: col=lane&15, row=quad*4+r
// XCD swizzle: tiles ordered x-fast/rb-major; chunk of 284 consecutive tiles per XCD
// so all 32 n-blocks of a row-tile share one XCD's L2 (A-tile fetched once per XCD).
__global__ __launch_bounds__(256) void k_gemm1(const unsigned short* __restrict__ Xc,
                                               const unsigned short* __restrict__ W1s,
                                               const int* __restrict__ offs,
                                               const float* __restrict__ b1,
                                               unsigned short* __restrict__ Hs) {
    constexpr int KB = H / 32;        // 32
    constexpr int MP = 36;            // epilogue LDS pad
    constexpr int NB = DFF / BN;      // 32
    constexpr int CPX = NB * (RBMAX - 1) / 8;   // 2272/8 = 284
    const int bid = blockIdx.x;
    const int t = (bid & 7) * CPX + (bid >> 3);
    const int rb = t / NB;
    if (rb * 128 >= offs[E]) return;
    int e = 0;
    while (e < E - 1 && rb * 128 >= offs[e + 1]) ++e;
    const int n0 = (t % NB) * BN;

    __shared__ unsigned short smem[4 * 128 * MP];   // 36 KB
    unsigned short* lds_a = smem;
    unsigned short* lds_b = smem + 4096;

    const int tid = threadIdx.x;
    const int wv = tid >> 6, ln = tid & 63;
    const int quad = ln >> 4, lr = ln & 15;
    const int wm = (wv & 1) * 64, wn = (wv >> 1) * 64;

    floatx4 acc[4][4];
#pragma unroll
    for (int i = 0; i < 4; ++i)
#pragma unroll
        for (int j = 0; j < 4; ++j) acc[i][j] = (floatx4){0.f, 0.f, 0.f, 0.f};

    const unsigned short* Atile = Xc + (size_t)rb * KB * 4096;
    const unsigned short* Btile = W1s + ((size_t)e * KB * DFF + n0) * 32;

    for (int kb = 0; kb < KB; ++kb) {
        __syncthreads();
        const unsigned short* a_src = Atile + (size_t)kb * 4096 + (wv * 2) * 512 + ln * 8;
        const unsigned short* b_src = Btile + (size_t)kb * DFF * 32 + (wv * 2) * 512 + ln * 8;
#pragma unroll
        for (int c = 0; c < 2; ++c) {
            gload16(a_src + c * 512, &lds_a[(wv * 2 + c) * 512]);
            gload16(b_src + c * 512, &lds_b[(wv * 2 + c) * 512]);
        }
        __syncthreads();
        bf16x8 af[4], bg[4];
#pragma unroll
        for (int i = 0; i < 4; ++i) {
            af[i] = *(const bf16x8*)(lds_a + (wm + i * 16 + lr) * 32 + quad * 8);
            bg[i] = *(const bf16x8*)(lds_b + (wn + i * 16 + lr) * 32 + quad * 8);
        }
#pragma unroll
        for (int i = 0; i < 4; ++i)
#pragma unroll
            for (int j = 0; j < 4; ++j)
                acc[i][j] = __builtin_amdgcn_mfma_f32_16x16x32_bf16(af[i], bg[j], acc[i][j], 0, 0, 0);
    }

    float bj[4];
#pragma unroll
    for (int j = 0; j < 4; ++j) bj[j] = b1[(size_t)e * DFF + n0 + wn + j * 16 + lr];
    __syncthreads();   // staging reads done; reuse smem for epilogue
#pragma unroll
    for (int j = 0; j < 4; ++j) {
        const int fl = wn + j * 16 + lr;
        const int fb = fl >> 5, f5 = fl & 31;
        unsigned short* dst = smem + fb * (128 * MP) + f5;
#pragma unroll
        for (int i = 0; i < 4; ++i) {
#pragma unroll
            for (int r = 0; r < 4; ++r) {
                const int m = wm + i * 16 + quad * 4 + r;
                float v = acc[i][j][r] + bj[j];
                // gelu(tanh): v*(1 - 1/(e^{2u}+1))
                float u = 0.79788456080286535588f * (v + 0.044715f * v * v * v);
                float ez = __expf(2.f * u);
                float g = v * (1.f - 1.f / (ez + 1.f));
                dst[m * MP] = f2bf(g);
            }
        }
    }
    __syncthreads();
    // coalesced copy-out: Hs chunk linear in g = fb*4096 + m*32 + f5
    const size_t hsbase = ((size_t)rb * 128 + (n0 >> 5)) * 4096;
#pragma unroll
    for (int it = 0; it < 8; ++it) {
        const int g = (it * 256 + tid) * 8;
        const int fb = g >> 12, rem = g & 4095, m = rem >> 5, f5 = rem & 31;
        const unsigned short* s = smem + fb * (128 * MP) + m * MP + f5;
        uint2 lo = *(const uint2*)s;
        uint2 hi = *(const uint2*)(s + 4);
        *(uint4*)(Hs + hsbase + (size_t)g) = make_uint4(lo.x, lo.y, hi.x, hi.y);
    }
}

// ---------------- GEMM2: Hs x W2[e], split-K=2, plain bf16 partial stores ----------------
// XCD swizzle: tiles ordered x-fast / (rb,ks)-major; chunk of 142 tiles per XCD so the
// 8 n-blocks sharing one 512KB A half-tile hit the same XCD L2 instead of 8 XCDs.
__global__ __launch_bounds__(256) void k_gemm2(const unsigned short* __restrict__ Hs,
                                               const unsigned short* __restrict__ W2s,
                                               const int* __restrict__ offs,
                                               const float* __restrict__ b2,
                                               unsigned short* __restrict__ P0,
                                               unsigned short* __restrict__ P1) {
    constexpr int KB = DFF / 32;      // 128
    constexpr int KBS = KB / 2;       // 64 per split
    constexpr int NB = H / BN;        // 8
    constexpr int CPX = NB * (RBMAX - 1) * 2 / 8;   // 1136/8 = 142
    const int bid = blockIdx.x;
    const int t = (bid & 7) * CPX + (bid >> 3);
    const int yz = t >> 3;            // 0..141
    const int rb = yz % (RBMAX - 1);
    const int ks = yz / (RBMAX - 1);
    if (rb * 128 >= offs[E]) return;
    int e = 0;
    while (e < E - 1 && rb * 128 >= offs[e + 1]) ++e;
    const int n0 = (t & 7) * BN;      // H: x<8

    __shared__ unsigned short smem[8192];
    unsigned short* lds_a = smem;
    unsigned short* lds_b = smem + 4096;

    const int tid = threadIdx.x;
    const int wv = tid >> 6, ln = tid & 63;
    const int quad = ln >> 4, lr = ln & 15;
    const int wm = (wv & 1) * 64, wn = (wv >> 1) * 64;

    floatx4 acc[4][4];
#pragma unroll
    for (int i = 0; i < 4; ++i)
#pragma unroll
        for (int j = 0; j < 4; ++j) acc[i][j] = (floatx4){0.f, 0.f, 0.f, 0.f};

    const unsigned short* Atile = Hs + (size_t)rb * KB * 4096;
    const unsigned short* Btile = W2s + ((size_t)e * KB * H + n0) * 32;

    for (int kb = ks * KBS; kb < ks * KBS + KBS; ++kb) {
        __syncthreads();
        const unsigned short* a_src = Atile + (size_t)kb * 4096 + (wv * 2) * 512 + ln * 8;
        const unsigned short* b_src = Btile + (size_t)kb * H * 32 + (wv * 2) * 512 + ln * 8;
#pragma unroll
        for (int c = 0; c < 2; ++c) {
            gload16(a_src + c * 512, &lds_a[(wv * 2 + c) * 512]);
            gload16(b_src + c * 512, &lds_b[(wv * 2 + c) * 512]);
        }
        __syncthreads();
        bf16x8 af[4], bg[4];
#pragma unroll
        for (int i = 0; i < 4; ++i) {
            af[i] = *(const bf16x8*)(lds_a + (wm + i * 16 + lr) * 32 + quad * 8);
            bg[i] = *(const bf16x8*)(lds_b + (wn + i * 16 + lr) * 32 + quad * 8);
        }
#pragma unroll
        for (int i = 0; i < 4; ++i)
#pragma unroll
            for (int j = 0; j < 4; ++j)
                acc[i][j] = __builtin_amdgcn_mfma_f32_16x16x32_bf16(af[i], bg[j], acc[i][j], 0, 0, 0);
    }

    float bj[4];
#pragma unroll
    for (int j = 0; j < 4; ++j)
        bj[j] = (ks == 0) ? b2[(size_t)e * H + n0 + wn + j * 16 + lr] : 0.f;
    unsigned short* P = ks ? P1 : P0;
#pragma unroll
    for (int i = 0; i < 4; ++i) {
#pragma unroll
        for (int r = 0; r < 4; ++r) {
            const int m = wm + i * 16 + quad * 4 + r;
            unsigned short* row = P + (size_t)(rb * 128 + m) * H + n0;
#pragma unroll
            for (int j = 0; j < 4; ++j)
                row[wn + j * 16 + lr] = f2bf(acc[i][j][r] + bj[j]);
        }
    }
}

// ---------------- final mix: out[t] = w0*(P0+P1)[pos0] + w1*(P0+P1)[pos1] ----------------
__global__ __launch_bounds__(256) void k_mix(const unsigned short* __restrict__ P0,
                                             const unsigned short* __restrict__ P1,
                                             const int* __restrict__ tok_pos,
                                             const float* __restrict__ rt_w,
                                             float* __restrict__ out) {
    const int t = blockIdx.x;
    const int c = threadIdx.x * 4;
    const int p0 = tok_pos[2 * t], p1 = tok_pos[2 * t + 1];
    const float w0 = rt_w[2 * t], w1 = rt_w[2 * t + 1];
    ushort4 a0 = *(const ushort4*)(P0 + (size_t)p0 * H + c);
    ushort4 a1 = *(const ushort4*)(P1 + (size_t)p0 * H + c);
    ushort4 b0 = *(const ushort4*)(P0 + (size_t)p1 * H + c);
    ushort4 b1 = *(const ushort4*)(P1 + (size_t)p1 * H + c);
    float4 o;
    o.x = w0 * (bf2f(a0.x) + bf2f(a1.x)) + w1 * (bf2f(b0.x) + bf2f(b1.x));
    o.y = w0 * (bf2f(a0.y) + bf2f(a1.y)) + w1 * (bf2f(b0.y) + bf2f(b1.y));
    o.z = w0 * (bf2f(a0.z) + bf2f(a1.z)) + w1 * (bf2f(b0.z) + bf2f(b1.z));
    o.w = w0 * (bf2f(a0.w) + bf2f(a1.w)) + w1 * (bf2f(b0.w) + bf2f(b1.w));
    *(float4*)(out + (size_t)t * H + c) = o;
}

extern "C" void kernel_launch(void* const* d_in, const int* in_sizes, int n_in,
                              void* d_out, int out_size, void* d_ws, size_t ws_size,
                              hipStream_t stream) {
    const float* x  = (const float*)d_in[0];
    const float* rw = (const float*)d_in[1];
    const float* w1 = (const float*)d_in[2];
    const float* b1 = (const float*)d_in[3];
    const float* w2 = (const float*)d_in[4];
    const float* b2 = (const float*)d_in[5];
    float* out = (float*)d_out;
    char* ws = (char*)d_ws;
    if (ws_size < WS_NEED) return;   // loud failure if scratch too small

    unsigned short* Ws   = (unsigned short*)(ws + OFF_WS);
    unsigned short* XcS  = (unsigned short*)(ws + OFF_XCS);   // Xc, later P0
    unsigned short* Hs   = (unsigned short*)(ws + OFF_HS);
    unsigned short* P1   = (unsigned short*)(ws + OFF_P1);
    int*   rt_idx   = (int*)(ws + OFF_RTIDX);
    float* rt_w     = (float*)(ws + OFF_RTW);
    int*   pair_tok = (int*)(ws + OFF_PTOK);
    float* pair_w   = (float*)(ws + OFF_PW);
    int*   tok_pos  = (int*)(ws + OFF_TOKPOS);
    int*   cnt      = (int*)(ws + OFF_CNT);
    int*   cur      = cnt + 8;
    int*   offs     = cnt + 16;

    hipMemsetAsync(cnt, 0, 128, stream);   // counts + cursors (+offs, rewritten)

    k_router<<<NTOK / 4, 256, 0, stream>>>(x, rw, rt_idx, rt_w, cnt);
    k_offsets<<<1, 64, 0, stream>>>(cnt, offs);
    k_scatter<<<NTOK / 256, 256, 0, stream>>>(rt_idx, rt_w, offs, cur, pair_tok, pair_w, tok_pos);
    k_gather<<<9216, 256, 0, stream>>>(x, offs, cnt, pair_tok, XcS);

    k_convert<H, DFF><<<8 * (H / 32) * (DFF / 128), 256, 0, stream>>>(w1, Ws);
    k_gemm1<<<32 * (RBMAX - 1), 256, 0, stream>>>(XcS, Ws, offs, b1, Hs);

    k_convert<DFF, H><<<8 * (DFF / 32) * (H / 128), 256, 0, stream>>>(w2, Ws);
    k_gemm2<<<8 * (RBMAX - 1) * 2, 256, 0, stream>>>(Hs, Ws, offs, b2, XcS, P1);

    k_mix<<<NTOK, 256, 0, stream>>>(XcS, P1, tok_pos, rt_w, out);
}

// Round 2
// 665.786 us; speedup vs baseline: 1.0434x; 1.0434x over previous
//
#include <hip/hip_runtime.h>
#include <hip/hip_bf16.h>
#include <stdint.h>

#define AS1 __attribute__((address_space(1)))
#define AS3 __attribute__((address_space(3)))

typedef __bf16 bf16x8 __attribute__((ext_vector_type(8)));
typedef float floatx4 __attribute__((ext_vector_type(4)));

static constexpr int NTOK = 4096;   // B*T
static constexpr int H    = 1024;
static constexpr int DFF  = 4096;
static constexpr int E    = 8;
static constexpr int BN   = 128;
static constexpr int RB   = 71;     // max 128-row tiles: ceil((8192+7*127)/128) = 71

// ---- workspace layout (bytes) ----
// No converted-weight buffer anymore (convert fused into GEMM B-staging).
static constexpr size_t OFF_XCS    = 0;            // 18,874,368  Xc (gemm1 A), bf16 octet layout
static constexpr size_t OFF_HS     = 18874368;     // 75,497,472  gelu(h) bf16 octet layout
static constexpr size_t OFF_P      = 94371840;     // 4 x 18,874,368 split-K partials (bf16)
static constexpr size_t PSZ        = 18874368;
static constexpr size_t OFF_RTIDX  = 169869312;    // 32 KB
static constexpr size_t OFF_RTW    = 169902080;    // 32 KB
static constexpr size_t OFF_PTOK   = 169934848;    // 36 KB
static constexpr size_t OFF_TOKPOS = 169971712;    // 32 KB
static constexpr size_t OFF_CNT    = 170004480;    // counts(8)+cursors(8)
static constexpr size_t WS_NEED    = 170004608;

__device__ __forceinline__ unsigned short f2bf(float f) {
    __bf16 b = (__bf16)f;
    return __builtin_bit_cast(unsigned short, b);
}
__device__ __forceinline__ float bf2f(unsigned short u) {
    unsigned int v = ((unsigned int)u) << 16;
    return __builtin_bit_cast(float, v);
}

__device__ __forceinline__ void gload16(const void* g, void* l) {
    // dest = wave-uniform lds base; HW scatters lane i at base + i*16
    __builtin_amdgcn_global_load_lds((AS1 void*)g, (AS3 void*)l, 16, 0, 0);
}

// padded prefix helpers (computed from counts[8] inline; k_offsets kernel removed)
__device__ __forceinline__ int find_expert_tot(const int* __restrict__ counts, int row, int* tot_out) {
    int e = 0, tot = 0;
#pragma unroll
    for (int i = 0; i < E; ++i) {
        int c = (counts[i] + 127) & ~127;
        if (row >= tot + c) e = i + 1;
        tot += c;
    }
    *tot_out = tot;
    return e;
}
__device__ __forceinline__ int padded_prefix(const int* __restrict__ counts, int e) {
    int o = 0;
#pragma unroll
    for (int i = 0; i < E; ++i) {
        int c = (counts[i] + 127) & ~127;
        o += (i < e) ? c : 0;
    }
    return o;
}

// ---------------- router: fp32 logits, top-2, softmax ----------------
__global__ __launch_bounds__(256) void k_router(const float* __restrict__ x,
                                                const float* __restrict__ rw,
                                                int* __restrict__ rt_idx,
                                                float* __restrict__ rt_w,
                                                int* __restrict__ counts) {
    const int wv = threadIdx.x >> 6, ln = threadIdx.x & 63;
    const int t = blockIdx.x * 4 + wv;
    const float* xr = x + (size_t)t * H + ln * 4;
    float4 xv[4];
#pragma unroll
    for (int c = 0; c < 4; ++c) xv[c] = *(const float4*)(xr + c * 256);
    float lg[E];
#pragma unroll
    for (int e = 0; e < E; ++e) {
        const float* rr = rw + (size_t)e * H + ln * 4;
        float acc = 0.f;
#pragma unroll
        for (int c = 0; c < 4; ++c) {
            float4 rv = *(const float4*)(rr + c * 256);
            acc += xv[c].x * rv.x + xv[c].y * rv.y + xv[c].z * rv.z + xv[c].w * rv.w;
        }
#pragma unroll
        for (int s = 32; s > 0; s >>= 1) acc += __shfl_xor(acc, s, 64);
        lg[e] = acc;
    }
    if (ln == 0) {
        int i0 = 0; float v0 = lg[0];
#pragma unroll
        for (int e = 1; e < E; ++e) if (lg[e] > v0) { v0 = lg[e]; i0 = e; }
        int i1 = -1; float v1 = -INFINITY;
#pragma unroll
        for (int e = 0; e < E; ++e) if (e != i0 && lg[e] > v1) { v1 = lg[e]; i1 = e; }
        float e1 = expf(v1 - v0);
        float inv = 1.f / (1.f + e1);
        rt_idx[2 * t] = i0; rt_idx[2 * t + 1] = i1;
        rt_w[2 * t] = inv;  rt_w[2 * t + 1] = e1 * inv;
        atomicAdd(&counts[i0], 1);
        atomicAdd(&counts[i1], 1);
    }
}

// ---------------- scatter pairs into expert segments (offsets inline) ----------------
__global__ __launch_bounds__(256) void k_scatter(const int* __restrict__ rt_idx,
                                                 const int* __restrict__ counts,
                                                 int* __restrict__ cursors,
                                                 int* __restrict__ pair_tok,
                                                 int* __restrict__ tok_pos) {
    int t = blockIdx.x * 256 + threadIdx.x;
    if (t >= NTOK) return;
    for (int k = 0; k < 2; ++k) {
        int e = rt_idx[2 * t + k];
        int p = atomicAdd(&cursors[e], 1);
        int pos = padded_prefix(counts, e) + p;
        pair_tok[pos] = t;
        tok_pos[2 * t + k] = pos;
    }
}

// ---------------- gather token rows -> bf16, 32-col chunked ----------------
// Xc_s[rb][kb][m][k%32] = x[tok(pos)][kb*32 + k%32],  pos = rb*128+m ; pad rows = 0
__global__ __launch_bounds__(256) void k_gather(const float* __restrict__ x,
                                                const int* __restrict__ counts,
                                                const int* __restrict__ pair_tok,
                                                unsigned short* __restrict__ xcs) {
    int pos = blockIdx.x;
    int tot;
    int e = find_expert_tot(counts, pos, &tot);
    if (pos >= tot) return;
    int off_e = padded_prefix(counts, e);
    bool valid = (pos - off_e) < counts[e];
    int tok = valid ? pair_tok[pos] : 0;
    int k0 = threadIdx.x * 4;
    float4 xv = valid ? *(const float4*)(x + (size_t)tok * H + k0)
                      : make_float4(0.f, 0.f, 0.f, 0.f);
    ushort4 o;
    o.x = f2bf(xv.x); o.y = f2bf(xv.y); o.z = f2bf(xv.z); o.w = f2bf(xv.w);
    int rb = pos >> 7, m = pos & 127;
    size_t idx = (((size_t)(rb * 32 + (k0 >> 5)) * 128 + m) * 32) + (k0 & 31);
    *(ushort4*)(xcs + idx) = o;
}

// ---------------- GEMM1: Xc[rows x 1024] x w1[e][1024 x 4096] (fp32, converted inline) ----------------
// A: bf16 octet layout via gload16 (unchanged). B: fp32 reg-staged, cvt, swizzled ds_write_b128.
// B LDS layout (shorts): n*32 + (kq ^ ((n>>1)&3))*8 + j, holding w[k0+kq*8+j][n].
// Write side: thread (kq=wave, sn) stages n=sn and n=sn+64 -> bank-floor writes.
// Read side:  lane (quad,lr) reads octet at n*32 + (quad ^ ((lr>>1)&3))*8 -> bank-floor reads.
__global__ __launch_bounds__(256) void k_gemm1(const unsigned short* __restrict__ Xc,
                                               const float* __restrict__ w1,
                                               const int* __restrict__ counts,
                                               const float* __restrict__ b1,
                                               unsigned short* __restrict__ Hs) {
    constexpr int KB = H / 32;        // 32
    constexpr int MP = 36;            // epilogue LDS pad
    constexpr int NB = DFF / BN;      // 32
    constexpr int CPX = NB * RB / 8;  // 2272/8 = 284
    const int bid = blockIdx.x;
    const int t = (bid & 7) * CPX + (bid >> 3);
    const int rb = t / NB;
    const int row = rb * 128;
    int tot;
    const int e = find_expert_tot(counts, row, &tot);
    if (row >= tot) return;
    const int n0 = (t % NB) * BN;

    __shared__ unsigned short smem[4 * 128 * MP];   // 36 KB
    unsigned short* lds_a = smem;
    unsigned short* lds_b = smem + 4096;

    const int tid = threadIdx.x;
    const int wv = tid >> 6, ln = tid & 63;
    const int quad = ln >> 4, lr = ln & 15;
    const int wm = (wv & 1) * 64, wn = (wv >> 1) * 64;
    const int bswz = quad ^ ((lr >> 1) & 3);

    // B staging ids: kq = wave, sn in 0..63 covers n = sn and sn+64
    const int skq = wv, sn = ln;
    const int sswz = skq ^ ((sn >> 1) & 3);
    const int wb1 = sn * 32 + sswz * 8;     // shorts
    const int wb2 = wb1 + 2048;

    floatx4 acc[4][4];
#pragma unroll
    for (int i = 0; i < 4; ++i)
#pragma unroll
        for (int j = 0; j < 4; ++j) acc[i][j] = (floatx4){0.f, 0.f, 0.f, 0.f};

    const unsigned short* Atile = Xc + (size_t)rb * KB * 4096;
    const float* Bsrc = w1 + ((size_t)e * H + skq * 8) * DFF + n0 + sn;

    float br[16];
#pragma unroll
    for (int j = 0; j < 8; ++j) {
        br[j]     = Bsrc[(size_t)j * DFF];
        br[8 + j] = Bsrc[(size_t)j * DFF + 64];
    }

    for (int kb = 0; kb < KB; ++kb) {
        __syncthreads();
        // stage B(kb): cvt regs -> swizzled LDS
        {
            union { unsigned short us[8]; uint4 v; } u1, u2;
#pragma unroll
            for (int j = 0; j < 8; ++j) { u1.us[j] = f2bf(br[j]); u2.us[j] = f2bf(br[8 + j]); }
            *(uint4*)(lds_b + wb1) = u1.v;
            *(uint4*)(lds_b + wb2) = u2.v;
        }
        // stage A(kb): async gload16
        const unsigned short* a_src = Atile + (size_t)kb * 4096 + (wv * 2) * 512 + ln * 8;
        gload16(a_src, &lds_a[(wv * 2) * 512]);
        gload16(a_src + 512, &lds_a[(wv * 2 + 1) * 512]);
        // prefetch B(kb+1) fp32 -> regs (drains at the same barrier as A's gload)
        {
            const int kbn = (kb + 1 < KB) ? kb + 1 : kb;
            const float* bs = Bsrc + (size_t)kbn * 32 * DFF;
#pragma unroll
            for (int j = 0; j < 8; ++j) {
                br[j]     = bs[(size_t)j * DFF];
                br[8 + j] = bs[(size_t)j * DFF + 64];
            }
        }
        __syncthreads();
        bf16x8 af[4], bg[4];
#pragma unroll
        for (int i = 0; i < 4; ++i) {
            af[i] = *(const bf16x8*)(lds_a + (wm + i * 16 + lr) * 32 + quad * 8);
            bg[i] = *(const bf16x8*)(lds_b + (wn + i * 16 + lr) * 32 + bswz * 8);
        }
#pragma unroll
        for (int i = 0; i < 4; ++i)
#pragma unroll
            for (int j = 0; j < 4; ++j)
                acc[i][j] = __builtin_amdgcn_mfma_f32_16x16x32_bf16(af[i], bg[j], acc[i][j], 0, 0, 0);
    }

    float bj[4];
#pragma unroll
    for (int j = 0; j < 4; ++j) bj[j] = b1[(size_t)e * DFF + n0 + wn + j * 16 + lr];
    __syncthreads();   // staging reads done; reuse smem for epilogue
#pragma unroll
    for (int j = 0; j < 4; ++j) {
        const int fl = wn + j * 16 + lr;
        const int fb = fl >> 5, f5 = fl & 31;
        unsigned short* dst = smem + fb * (128 * MP) + f5;
#pragma unroll
        for (int i = 0; i < 4; ++i) {
#pragma unroll
            for (int r = 0; r < 4; ++r) {
                const int m = wm + i * 16 + quad * 4 + r;
                float v = acc[i][j][r] + bj[j];
                // gelu(tanh): v*(1 - 1/(e^{2u}+1))
                float u = 0.79788456080286535588f * (v + 0.044715f * v * v * v);
                float ez = __expf(2.f * u);
                float g = v * (1.f - 1.f / (ez + 1.f));
                dst[m * MP] = f2bf(g);
            }
        }
    }
    __syncthreads();
    // coalesced copy-out: Hs chunk linear in g = fb*4096 + m*32 + f5
    const size_t hsbase = ((size_t)rb * 128 + (n0 >> 5)) * 4096;
#pragma unroll
    for (int it = 0; it < 8; ++it) {
        const int g = (it * 256 + tid) * 8;
        const int fb = g >> 12, rem = g & 4095, m = rem >> 5, f5 = rem & 31;
        const unsigned short* s = smem + fb * (128 * MP) + m * MP + f5;
        uint2 lo = *(const uint2*)s;
        uint2 hi = *(const uint2*)(s + 4);
        *(uint4*)(Hs + hsbase + (size_t)g) = make_uint4(lo.x, lo.y, hi.x, hi.y);
    }
}

// ---------------- GEMM2: Hs x w2[e] (fp32, converted inline), split-K=4 ----------------
__global__ __launch_bounds__(256) void k_gemm2(const unsigned short* __restrict__ Hs,
                                               const float* __restrict__ w2,
                                               const int* __restrict__ counts,
                                               const float* __restrict__ b2,
                                               unsigned short* __restrict__ Pb) {
    constexpr int KB = DFF / 32;      // 128
    constexpr int NSPLIT = 4;
    constexpr int KBS = KB / NSPLIT;  // 32
    constexpr int NB = H / BN;        // 8
    constexpr int CPX = NB * RB * NSPLIT / 8;   // 2272/8 = 284
    const int bid = blockIdx.x;
    const int t = (bid & 7) * CPX + (bid >> 3);
    const int nb = t & 7;
    const int rest = t >> 3;          // 0..283
    const int rb = rest % RB;
    const int ks = rest / RB;         // 0..3
    const int row = rb * 128;
    int tot;
    const int e = find_expert_tot(counts, row, &tot);
    if (row >= tot) return;
    const int n0 = nb * BN;

    __shared__ unsigned short smem[8192];
    unsigned short* lds_a = smem;
    unsigned short* lds_b = smem + 4096;

    const int tid = threadIdx.x;
    const int wv = tid >> 6, ln = tid & 63;
    const int quad = ln >> 4, lr = ln & 15;
    const int wm = (wv & 1) * 64, wn = (wv >> 1) * 64;
    const int bswz = quad ^ ((lr >> 1) & 3);

    const int skq = wv, sn = ln;
    const int sswz = skq ^ ((sn >> 1) & 3);
    const int wb1 = sn * 32 + sswz * 8;
    const int wb2 = wb1 + 2048;

    floatx4 acc[4][4];
#pragma unroll
    for (int i = 0; i < 4; ++i)
#pragma unroll
        for (int j = 0; j < 4; ++j) acc[i][j] = (floatx4){0.f, 0.f, 0.f, 0.f};

    const unsigned short* Atile = Hs + ((size_t)rb * KB + ks * KBS) * 4096;
    const float* Bsrc = w2 + ((size_t)e * DFF + ks * KBS * 32 + skq * 8) * H + n0 + sn;

    float br[16];
#pragma unroll
    for (int j = 0; j < 8; ++j) {
        br[j]     = Bsrc[(size_t)j * H];
        br[8 + j] = Bsrc[(size_t)j * H + 64];
    }

    for (int kb = 0; kb < KBS; ++kb) {
        __syncthreads();
        {
            union { unsigned short us[8]; uint4 v; } u1, u2;
#pragma unroll
            for (int j = 0; j < 8; ++j) { u1.us[j] = f2bf(br[j]); u2.us[j] = f2bf(br[8 + j]); }
            *(uint4*)(lds_b + wb1) = u1.v;
            *(uint4*)(lds_b + wb2) = u2.v;
        }
        const unsigned short* a_src = Atile + (size_t)kb * 4096 + (wv * 2) * 512 + ln * 8;
        gload16(a_src, &lds_a[(wv * 2) * 512]);
        gload16(a_src + 512, &lds_a[(wv * 2 + 1) * 512]);
        {
            const int kbn = (kb + 1 < KBS) ? kb + 1 : kb;
            const float* bs = Bsrc + (size_t)kbn * 32 * H;
#pragma unroll
            for (int j = 0; j < 8; ++j) {
                br[j]     = bs[(size_t)j * H];
                br[8 + j] = bs[(size_t)j * H + 64];
            }
        }
        __syncthreads();
        bf16x8 af[4], bg[4];
#pragma unroll
        for (int i = 0; i < 4; ++i) {
            af[i] = *(const bf16x8*)(lds_a + (wm + i * 16 + lr) * 32 + quad * 8);
            bg[i] = *(const bf16x8*)(lds_b + (wn + i * 16 + lr) * 32 + bswz * 8);
        }
#pragma unroll
        for (int i = 0; i < 4; ++i)
#pragma unroll
            for (int j = 0; j < 4; ++j)
                acc[i][j] = __builtin_amdgcn_mfma_f32_16x16x32_bf16(af[i], bg[j], acc[i][j], 0, 0, 0);
    }

    float bj[4];
#pragma unroll
    for (int j = 0; j < 4; ++j)
        bj[j] = (ks == 0) ? b2[(size_t)e * H + n0 + wn + j * 16 + lr] : 0.f;
    unsigned short* P = Pb + (size_t)ks * (PSZ / 2);
#pragma unroll
    for (int i = 0; i < 4; ++i) {
#pragma unroll
        for (int r = 0; r < 4; ++r) {
            const int m = wm + i * 16 + quad * 4 + r;
            unsigned short* rowp = P + (size_t)(rb * 128 + m) * H + n0;
#pragma unroll
            for (int j = 0; j < 4; ++j)
                rowp[wn + j * 16 + lr] = f2bf(acc[i][j][r] + bj[j]);
        }
    }
}

// ---------------- final mix: out[t] = w0*sum_ks P[ks][pos0] + w1*sum_ks P[ks][pos1] ----------------
__global__ __launch_bounds__(256) void k_mix(const unsigned short* __restrict__ Pb,
                                             const int* __restrict__ tok_pos,
                                             const float* __restrict__ rt_w,
                                             float* __restrict__ out) {
    const int t = blockIdx.x;
    const int c = threadIdx.x * 4;
    const int p0 = tok_pos[2 * t], p1 = tok_pos[2 * t + 1];
    const float w0 = rt_w[2 * t], w1 = rt_w[2 * t + 1];
    float4 s0 = make_float4(0.f, 0.f, 0.f, 0.f);
    float4 s1 = make_float4(0.f, 0.f, 0.f, 0.f);
#pragma unroll
    for (int q = 0; q < 4; ++q) {
        const unsigned short* P = Pb + (size_t)q * (PSZ / 2);
        ushort4 a = *(const ushort4*)(P + (size_t)p0 * H + c);
        ushort4 b = *(const ushort4*)(P + (size_t)p1 * H + c);
        s0.x += bf2f(a.x); s0.y += bf2f(a.y); s0.z += bf2f(a.z); s0.w += bf2f(a.w);
        s1.x += bf2f(b.x); s1.y += bf2f(b.y); s1.z += bf2f(b.z); s1.w += bf2f(b.w);
    }
    float4 o;
    o.x = w0 * s0.x + w1 * s1.x;
    o.y = w0 * s0.y + w1 * s1.y;
    o.z = w0 * s0.z + w1 * s1.z;
    o.w = w0 * s0.w + w1 * s1.w;
    *(float4*)(out + (size_t)t * H + c) = o;
}

extern "C" void kernel_launch(void* const* d_in, const int* in_sizes, int n_in,
                              void* d_out, int out_size, void* d_ws, size_t ws_size,
                              hipStream_t stream) {
    const float* x  = (const float*)d_in[0];
    const float* rw = (const float*)d_in[1];
    const float* w1 = (const float*)d_in[2];
    const float* b1 = (const float*)d_in[3];
    const float* w2 = (const float*)d_in[4];
    const float* b2 = (const float*)d_in[5];
    float* out = (float*)d_out;
    char* ws = (char*)d_ws;
    if (ws_size < WS_NEED) return;   // loud failure if scratch too small

    unsigned short* XcS = (unsigned short*)(ws + OFF_XCS);
    unsigned short* Hs  = (unsigned short*)(ws + OFF_HS);
    unsigned short* Pb  = (unsigned short*)(ws + OFF_P);
    int*   rt_idx   = (int*)(ws + OFF_RTIDX);
    float* rt_w     = (float*)(ws + OFF_RTW);
    int*   pair_tok = (int*)(ws + OFF_PTOK);
    int*   tok_pos  = (int*)(ws + OFF_TOKPOS);
    int*   cnt      = (int*)(ws + OFF_CNT);
    int*   cur      = cnt + 8;

    hipMemsetAsync(cnt, 0, 128, stream);   // counts + cursors

    k_router<<<NTOK / 4, 256, 0, stream>>>(x, rw, rt_idx, rt_w, cnt);
    k_scatter<<<NTOK / 256, 256, 0, stream>>>(rt_idx, cnt, cur, pair_tok, tok_pos);
    k_gather<<<RB * 128, 256, 0, stream>>>(x, cnt, pair_tok, XcS);

    k_gemm1<<<(DFF / BN) * RB, 256, 0, stream>>>(XcS, w1, cnt, b1, Hs);
    k_gemm2<<<(H / BN) * RB * 4, 256, 0, stream>>>(Hs, w2, cnt, b2, Pb);

    k_mix<<<NTOK, 256, 0, stream>>>(Pb, tok_pos, rt_w, out);
}